// Round 12
// baseline (446.246 us; speedup 1.0000x reference)
//
#include <hip/hip_runtime.h>
#include <hip/hip_fp16.h>
#include <stdint.h>
#include <stddef.h>

// Problem shape (hard-coded to the reference setup_inputs)
#define MM 4096            // tokens
#define NN 11008           // output cols
#define KK 4096            // reduction
#define NQ (NN / 8)        // packed cols = 1376

// 256x256 tile, BK=32, 512 threads (8 waves: 2M x 4N), 32x32x16 MFMA,
// ring-3 LDS (96KB), 2 phases/tile, counted vmcnt(2) never drained.
#define BM 256
#define BN 256
#define BK 32
#define NKT (KK / BK)      // 128 K-tiles
#define GRID_N (NN / BN)   // 43
#define GRID_M (MM / BM)   // 16
#define NWG (GRID_N * GRID_M)  // 688 = 8 XCD * 86

typedef _Float16 half8 __attribute__((ext_vector_type(8)));
typedef _Float16 half2v __attribute__((ext_vector_type(2)));
typedef float f32x16 __attribute__((ext_vector_type(16)));
typedef float f32x4 __attribute__((ext_vector_type(4)));
typedef uint32_t uint4v __attribute__((ext_vector_type(4)));

union U1H2 { uint32_t u; half2v h; };
union U4H8 { uint4v u; half8 h; };

__device__ __forceinline__ void gload_lds16(const void* g, void* l) {
  __builtin_amdgcn_global_load_lds(
      (const __attribute__((address_space(1))) uint32_t*)g,
      (__attribute__((address_space(3))) uint32_t*)l, 16, 0, 0);
}

// ---------------- prepass 1: x f32 -> f16 (linear [m][k]) ----------------
__global__ __launch_bounds__(256) void convert_x_kernel(const float* __restrict__ x,
                                                        _Float16* __restrict__ xh) {
  const int idx = (blockIdx.x * 256 + threadIdx.x) * 8;
  const float4* p = reinterpret_cast<const float4*>(x + idx);
  float4 a = p[0], b = p[1];
  U4H8 r;
  r.h[0] = (_Float16)a.x; r.h[1] = (_Float16)a.y;
  r.h[2] = (_Float16)a.z; r.h[3] = (_Float16)a.w;
  r.h[4] = (_Float16)b.x; r.h[5] = (_Float16)b.y;
  r.h[6] = (_Float16)b.z; r.h[7] = (_Float16)b.w;
  *reinterpret_cast<uint4v*>(xh + idx) = r.u;
}

// ---------------- prepass 2: AWQ dequant -> W' fp16, layout [k/8][n][8] ---
__global__ __launch_bounds__(256) void dequant_w_kernel(const uint32_t* __restrict__ qw,
                                                        const float* __restrict__ sc,
                                                        const uint32_t* __restrict__ qz,
                                                        _Float16* __restrict__ w1) {
  const int T = blockIdx.x * 256 + threadIdx.x;  // 512*1376 threads exactly
  const int qc = T % NQ;
  const int kb8 = T / NQ;                        // k-block of 8
  const int g = kb8 >> 4;                        // group of 128 k

  const uint32_t* qp = qw + (size_t)(kb8 * 8) * NQ + qc;
  uint32_t q[8];
#pragma unroll
  for (int j = 0; j < 8; ++j) q[j] = qp[(size_t)j * NQ];

  const uint32_t zq = qz[(size_t)g * NQ + qc];
  const float* sp = sc + (size_t)g * NN + qc * 8;
  float4 s0 = *reinterpret_cast<const float4*>(sp);
  float4 s1 = *reinterpret_cast<const float4*>(sp + 4);
  const float sv[8] = {s0.x, s0.y, s0.z, s0.w, s1.x, s1.y, s1.z, s1.w};

  _Float16* op = w1 + ((size_t)kb8 * NN + (size_t)qc * 8) * 8;
#pragma unroll
  for (int c = 0; c < 8; ++c) {
    const int sh = ((c >> 1) << 2) + ((c & 1) << 4);  // AWQ col->shift
    uint32_t zc = ((zq >> sh) & 15u) | 0x6400u;       // fp16 1024+z
    zc |= zc << 16;
    U1H2 uz; uz.u = zc;
    const _Float16 hs = (_Float16)sv[c];
    half2v s2 = {hs, hs};
    uint4v outp;
#pragma unroll
    for (int i = 0; i < 4; ++i) {
      const uint32_t lo = (q[2 * i] >> sh) & 15u;
      const uint32_t hi = (q[2 * i + 1] >> sh) & 15u;
      U1H2 uw; uw.u = lo | (hi << 16) | 0x64006400u;
      U1H2 ur; ur.h = (uw.h - uz.h) * s2;             // exact sub, scale
      outp[i] = ur.u;
    }
    *reinterpret_cast<uint4v*>(op + c * 8) = outp;
  }
}

// ---------------- main: 32x32x16 MFMA, ring-3, read-ahead pipeline --------
// LDS 96KB, 3 units of (A 16KB + B 16KB). BOTH operands now use the proven
// contiguous family (R3..R10 B-pattern, measured 0 conflicts):
//   A unit: [4 u][256 rows][8 halfs]  -- frag read = contiguous 512B per
//   32-lane half (byte = u*4096 + row*16); R11's [row-pair][slot] layout had
//   row stride 128B = bank-wrap -> row dropped out of bank index (2.25e7
//   conflicts, = R3's count).
//   B unit: [4 kb][256 n][8] (unchanged, proven).
// Tile t in unit t%3; tile t+2 staged during t's 2 phases. VMC(2) at end of
// ph0 retires A(t+1),B(t+1); never drained. LGKM(6) certifies the previous
// phase's 6 ds_reads (4 A + 2 B).
__global__ __launch_bounds__(512, 2)
void gemm_pipe(const _Float16* __restrict__ xh, const _Float16* __restrict__ w1,
               float* __restrict__ out) {
  __shared__ __align__(16) _Float16 S[49152];   // 96 KB

  const int tid = threadIdx.x;
  const int lane = tid & 63;
  const int wid = tid >> 6;       // 0..7
  const int wm = wid >> 2;        // 0..1  (M half: 128 rows)
  const int wn = wid & 3;         // 0..3  (N quarter: 64 cols)
  const int l31 = lane & 31;
  const int lh = lane >> 5;       // 0/1: k-half of fragment

  // XCD swizzle: XCD owns 2 m-panels x all 43 n-panels, n-major
  const int wg = blockIdx.x;
  const int xcd = wg & 7;
  const int j = wg >> 3;                        // 0..85
  const int m0 = (xcd * 2 + (j & 1)) * BM;
  const int n0 = (j >> 1) * BN;

  // ---- staging sources (chunk c = instr*512 + tid, 16B per chunk) ----
  // A: u = c>>8 (k-chunk 0..3), row = c&255 -> linear LDS [u][row][8]
  const int c0 = tid, c1 = 512 + tid;
  const _Float16* aS0 = xh + (size_t)(m0 + (c0 & 255)) * KK + (c0 >> 8) * 8;
  const _Float16* aS1 = xh + (size_t)(m0 + (c1 & 255)) * KK + (c1 >> 8) * 8;
  // B: kb = c>>8, n = c&255 (linear)
  const _Float16* bS0 = w1 + ((size_t)(c0 >> 8) * NN + n0 + (c0 & 255)) * 8;
  const _Float16* bS1 = w1 + ((size_t)(c1 >> 8) * NN + n0 + (c1 & 255)) * 8;

  // ---- LDS read offsets (halfs) ----
  // A frag: u = kstep*2 + lh, row = wm*128 + mb*32 + l31
  //   addr = unit*8192 + u*2048 + row*8  (wm*128*8 = wm*1024; mb adds mb*256)
  const int vA0 = lh * 2048 + (wm * 128 + l31) * 8;   // kstep0; + mb*256
  const int vA1 = vA0 + 4096;                          // kstep1 (u += 2)
  // B frag: kb = kstep*2 + lh, n = wn*64 + nb*32 + l31
  const int vB0 = lh * 2048 + (wn * 64 + l31) * 8;    // + nb*256 + 24576
  const int vB1 = vB0 + 4096;

  f32x16 acc[8];   // [mb*2+nb], mb 0..3, nb 0..1
#pragma unroll
  for (int i = 0; i < 8; ++i)
#pragma unroll
    for (int e = 0; e < 16; ++e) acc[i][e] = 0.f;

  half8 af0[4], af1[4], bf0[2], bf1[2];

#define RD_A(DST, U, VAX)                                                      \
  _Pragma("unroll") for (int mb = 0; mb < 4; ++mb)                             \
      DST[mb] = *reinterpret_cast<const half8*>(                               \
          &S[(U) * 8192 + mb * 256 + (VAX)]);

#define RD_B(DST, U, VBX)                                                      \
  _Pragma("unroll") for (int nb = 0; nb < 2; ++nb)                             \
      DST[nb] = *reinterpret_cast<const half8*>(                               \
          &S[24576 + (U) * 8192 + nb * 256 + (VBX)]);

#define MFMA8(AREG, BREG)                                                      \
  _Pragma("unroll") for (int mb = 0; mb < 4; ++mb)                             \
      _Pragma("unroll") for (int nb = 0; nb < 2; ++nb)                         \
          acc[mb * 2 + nb] = __builtin_amdgcn_mfma_f32_32x32x16_f16(           \
              AREG[mb], BREG[nb], acc[mb * 2 + nb], 0, 0, 0);

#define STG_A(U, TOFF)                                                         \
  gload_lds16(aS0 + (size_t)(TOFF) * BK, &S[(U) * 8192 + wid * 512]);          \
  gload_lds16(aS1 + (size_t)(TOFF) * BK, &S[(U) * 8192 + 4096 + wid * 512]);

#define STG_B(U, TOFF)                                                         \
  gload_lds16(bS0 + (size_t)(TOFF) * NN * 32,                                  \
              &S[24576 + (U) * 8192 + wid * 512]);                             \
  gload_lds16(bS1 + (size_t)(TOFF) * NN * 32,                                  \
              &S[24576 + (U) * 8192 + 4096 + wid * 512]);

#define BARRIER __builtin_amdgcn_s_barrier()
#define LGKM(N) asm volatile("s_waitcnt lgkmcnt(" #N ")" ::: "memory")
#define VMC(N) asm volatile("s_waitcnt vmcnt(" #N ")" ::: "memory")
#define SB0 __builtin_amdgcn_sched_barrier(0)
#define PRIO1 __builtin_amdgcn_s_setprio(1)
#define PRIO0 __builtin_amdgcn_s_setprio(0)

// Tile T lives in unit U0; next tile in U1; stage T+2 into U2.
#define TILE(T, U0, U1, U2)                                                    \
  {                                                                            \
    /* ph0: MFMA kstep0 (af0,bf0); prefetch kstep1 frags; stage A(T+2) */      \
    BARRIER; SB0;                                                              \
    RD_A(af1, U0, vA1)                                                         \
    RD_B(bf1, U0, vB1)                                                         \
    STG_A(U2, ((T) + 2) & (NKT - 1))                                           \
    LGKM(6); SB0;                                                              \
    PRIO1; MFMA8(af0, bf0) PRIO0;                                              \
    VMC(2);                                                                    \
    /* ph1: MFMA kstep1 (af1,bf1); prefetch T+1 kstep0; stage B(T+2) */        \
    BARRIER; SB0;                                                              \
    RD_A(af0, U1, vA0)                                                         \
    RD_B(bf0, U1, vB0)                                                         \
    STG_B(U2, ((T) + 2) & (NKT - 1))                                           \
    LGKM(6); SB0;                                                              \
    PRIO1; MFMA8(af1, bf1) PRIO0;                                              \
  }

  // ---- prologue: stage tiles 0 (unit0), 1 (unit1); certify tile 0 ----
  STG_A(0, 0)
  STG_B(0, 0)
  STG_A(1, 1)
  STG_B(1, 1)
  VMC(4);            // A(0),B(0) landed; A(1),B(1) in flight
  BARRIER; SB0;
  RD_A(af0, 0, vA0)  // kstep0 of tile 0
  RD_B(bf0, 0, vB0)

  for (int it = 0; it < 42; ++it) {
    const int t0 = it * 3;
    TILE(t0, 0, 1, 2)
    TILE(t0 + 1, 1, 2, 0)
    TILE(t0 + 2, 2, 0, 1)
  }
  TILE(126, 0, 1, 2)
  TILE(127, 1, 2, 0)

#undef TILE
#undef RD_A
#undef RD_B
#undef MFMA8
#undef STG_A
#undef STG_B

  // ---- epilogue: 32x32 C/D layout col=lane&31, row=(reg&3)+8*(reg>>2)+4*lh
  float* op = out + (size_t)(m0 + wm * 128) * NN + (n0 + wn * 64);
#pragma unroll
  for (int mb = 0; mb < 4; ++mb)
#pragma unroll
    for (int nb = 0; nb < 2; ++nb)
#pragma unroll
      for (int g = 0; g < 4; ++g)
#pragma unroll
        for (int e = 0; e < 4; ++e) {
          const int row = mb * 32 + 4 * lh + 8 * g + e;
          const int col = nb * 32 + l31;
          op[(size_t)row * NN + col] = acc[mb * 2 + nb][g * 4 + e];
        }
}

// ---------------- fallback: inline-dequant GEMM (small workspace) ---------
template <bool APRE>
__global__ __launch_bounds__(256)
void awq_gemm(const float* __restrict__ x, const _Float16* __restrict__ xh,
              const uint32_t* __restrict__ qw, const float* __restrict__ sc,
              const uint32_t* __restrict__ qz, float* __restrict__ out) {
  __shared__ __align__(16) _Float16 Asf[128 * 64];
  __shared__ __align__(16) _Float16 Bsf[128 * 64];

  const int tid = threadIdx.x;
  const int lane = tid & 63;
  const int wid = tid >> 6;
  const int wr = wid >> 1;
  const int wc = wid & 1;
  const int n0 = blockIdx.x * 128;
  const int m0 = blockIdx.y * 128;
  const int lr = lane & 15;
  const int lq = lane >> 4;

  const int bn = tid & 127;
  const int bh = tid >> 7;
  const int gn = n0 + bn;
  const int qc = gn >> 3;
  const int jj = gn & 7;
  const int shift = ((jj >> 1) << 2) + ((jj & 1) << 4);

  const int ar = tid >> 1;
  const int ah = tid & 1;

  f32x4 acc[4][4];
  const f32x4 fz = {0.f, 0.f, 0.f, 0.f};
#pragma unroll
  for (int i = 0; i < 4; ++i)
#pragma unroll
    for (int jn = 0; jn < 4; ++jn) acc[i][jn] = fz;

  half2v zsp = {(_Float16)0.f, (_Float16)0.f};
  half2v ssp = {(_Float16)0.f, (_Float16)0.f};

  for (int kt = 0; kt < KK / 64; ++kt) {
    const int k0 = kt * 64;
    if ((kt & 1) == 0) {
      const int g = k0 >> 7;
      const uint32_t zq = qz[(size_t)g * NQ + qc];
      uint32_t zm = ((zq >> shift) & 15u) | 0x6400u;
      zm |= zm << 16;
      U1H2 uz; uz.u = zm; zsp = uz.h;
      const float s = sc[(size_t)g * NN + gn];
      const _Float16 hs = (_Float16)s;
      ssp[0] = hs; ssp[1] = hs;
    }
    __syncthreads();
    if (APRE) {
#pragma unroll
      for (int i = 0; i < 4; ++i) {
        const int cbase = (i * 4 + wid) * 64;
        const int chunk = cbase + lane;
        const int mrow = chunk >> 3;
        const int slot = (chunk & 7) ^ (mrow & 7);
        const _Float16* gp = xh + (size_t)(m0 + mrow) * KK + k0 + slot * 8;
        gload_lds16(gp, (void*)&Asf[cbase * 8]);
      }
    } else {
      const float* xp = x + (size_t)(m0 + ar) * KK + k0 + ah * 32;
#pragma unroll
      for (int j2 = 0; j2 < 4; ++j2) {
        float4 a4 = *reinterpret_cast<const float4*>(xp + j2 * 8);
        float4 b4 = *reinterpret_cast<const float4*>(xp + j2 * 8 + 4);
        U4H8 r;
        r.h[0] = (_Float16)a4.x; r.h[1] = (_Float16)a4.y;
        r.h[2] = (_Float16)a4.z; r.h[3] = (_Float16)a4.w;
        r.h[4] = (_Float16)b4.x; r.h[5] = (_Float16)b4.y;
        r.h[6] = (_Float16)b4.z; r.h[7] = (_Float16)b4.w;
        const int slot = (ah * 4 + j2) ^ (ar & 7);
        *reinterpret_cast<uint4v*>(&Asf[ar * 64 + slot * 8]) = r.u;
      }
    }
    {
      const uint32_t* qp = qw + (size_t)(k0 + bh * 32) * NQ + qc;
#pragma unroll
      for (int f = 0; f < 4; ++f) {
        uint32_t qv[8];
#pragma unroll
        for (int jv = 0; jv < 8; ++jv) qv[jv] = qp[(size_t)(f * 8 + jv) * NQ];
        uint4v wp;
#pragma unroll
        for (int p = 0; p < 4; ++p) {
          const uint32_t lo = (qv[2 * p] >> shift) & 15u;
          const uint32_t hi = (qv[2 * p + 1] >> shift);
          const uint32_t w01 = (((hi << 16) | lo) & 0x000F000Fu) | 0x64006400u;
          U1H2 uw; uw.u = w01;
          U1H2 ur; ur.h = (uw.h - zsp) * ssp;
          wp[p] = ur.u;
        }
        const int slot = (bh * 4 + f) ^ (bn & 7);
        *reinterpret_cast<uint4v*>(&Bsf[bn * 64 + slot * 8]) = wp;
      }
    }
    __syncthreads();
#pragma unroll
    for (int kq = 0; kq < 2; ++kq) {
      half8 af[4], bf[4];
#pragma unroll
      for (int mi = 0; mi < 4; ++mi) {
        const int am = wr * 64 + mi * 16 + lr;
        const int aslot = (kq * 4 + lq) ^ (am & 7);
        af[mi] = *reinterpret_cast<const half8*>(&Asf[am * 64 + aslot * 8]);
      }
#pragma unroll
      for (int ni = 0; ni < 4; ++ni) {
        const int bn2 = wc * 64 + ni * 16 + lr;
        const int bslot = (kq * 4 + lq) ^ (bn2 & 7);
        bf[ni] = *reinterpret_cast<const half8*>(&Bsf[bn2 * 64 + bslot * 8]);
      }
#pragma unroll
      for (int mi = 0; mi < 4; ++mi)
#pragma unroll
        for (int ni = 0; ni < 4; ++ni)
          acc[mi][ni] = __builtin_amdgcn_mfma_f32_16x16x32_f16(af[mi], bf[ni], acc[mi][ni], 0, 0, 0);
    }
  }

  float* op = out + (size_t)(m0 + wr * 64) * NN + (n0 + wc * 64);
#pragma unroll
  for (int mi = 0; mi < 4; ++mi)
#pragma unroll
    for (int ni = 0; ni < 4; ++ni)
#pragma unroll
      for (int i = 0; i < 4; ++i) {
        const int row = mi * 16 + lq * 4 + i;
        const int col = ni * 16 + lr;
        op[(size_t)row * NN + col] = acc[mi][ni][i];
      }
}

extern "C" void kernel_launch(void* const* d_in, const int* in_sizes, int n_in,
                              void* d_out, int out_size, void* d_ws, size_t ws_size,
                              hipStream_t stream) {
  const float* x = (const float*)d_in[0];
  const uint32_t* qw = (const uint32_t*)d_in[1];
  const float* sc = (const float*)d_in[2];
  const uint32_t* qz = (const uint32_t*)d_in[3];
  float* out = (float*)d_out;

  const size_t xh_bytes = (size_t)MM * KK * sizeof(_Float16);   // 33.5 MB
  const size_t w1_bytes = (size_t)KK * NN * sizeof(_Float16);   // 90.2 MB

  if (ws_size >= xh_bytes + w1_bytes) {
    _Float16* xh = (_Float16*)d_ws;
    _Float16* w1 = (_Float16*)((char*)d_ws + xh_bytes);
    convert_x_kernel<<<(MM * KK) / (256 * 8), 256, 0, stream>>>(x, xh);
    dequant_w_kernel<<<(KK / 8) * NQ / 256, 256, 0, stream>>>(qw, sc, qz, w1);
    gemm_pipe<<<NWG, 512, 0, stream>>>(xh, w1, out);
  } else if (ws_size >= xh_bytes) {
    _Float16* xh = (_Float16*)d_ws;
    convert_x_kernel<<<(MM * KK) / (256 * 8), 256, 0, stream>>>(x, xh);
    awq_gemm<true><<<dim3(NN / 128, MM / 128), 256, 0, stream>>>(x, xh, qw, sc, qz, out);
  } else {
    awq_gemm<false><<<dim3(NN / 128, MM / 128), 256, 0, stream>>>(x, nullptr, qw, sc, qz, out);
  }
}

// Round 13
// 382.116 us; speedup vs baseline: 1.1678x; 1.1678x over previous
//
#include <hip/hip_runtime.h>
#include <hip/hip_fp16.h>
#include <stdint.h>
#include <stddef.h>

// Problem shape (hard-coded to the reference setup_inputs)
#define MM 4096            // tokens
#define NN 11008           // output cols
#define KK 4096            // reduction
#define NQ (NN / 8)        // packed cols = 1376

// 256x256 tile, BK=64, 512 threads (8 waves: 2M x 4N), LDS double-buffer,
// k-split half-tiles (16KB each), 4 phases/tile, read-ahead pipeline.
// == R10, the best-measured configuration: GEMM 332us, MfmaUtil 53.6%. ==
#define BM 256
#define BN 256
#define BK 64
#define NKT (KK / BK)      // 64 K-tiles
#define GRID_N (NN / BN)   // 43
#define GRID_M (MM / BM)   // 16
#define NWG (GRID_N * GRID_M)  // 688 = 8 XCD * 86

// LDS map (halfs): A halves at (buf*2+kk)*8192; B at 32768 + same. 128 KB.
#define HT 8192

typedef _Float16 half8 __attribute__((ext_vector_type(8)));
typedef _Float16 half2v __attribute__((ext_vector_type(2)));
typedef float f32x4 __attribute__((ext_vector_type(4)));
typedef uint32_t uint4v __attribute__((ext_vector_type(4)));

union U1H2 { uint32_t u; half2v h; };
union U4H8 { uint4v u; half8 h; };

__device__ __forceinline__ void gload_lds16(const void* g, void* l) {
  __builtin_amdgcn_global_load_lds(
      (const __attribute__((address_space(1))) uint32_t*)g,
      (__attribute__((address_space(3))) uint32_t*)l, 16, 0, 0);
}

// ---------------- prepass 1: x f32 -> f16 (linear [m][k]) ----------------
__global__ __launch_bounds__(256) void convert_x_kernel(const float* __restrict__ x,
                                                        _Float16* __restrict__ xh) {
  const int idx = (blockIdx.x * 256 + threadIdx.x) * 8;
  const float4* p = reinterpret_cast<const float4*>(x + idx);
  float4 a = p[0], b = p[1];
  U4H8 r;
  r.h[0] = (_Float16)a.x; r.h[1] = (_Float16)a.y;
  r.h[2] = (_Float16)a.z; r.h[3] = (_Float16)a.w;
  r.h[4] = (_Float16)b.x; r.h[5] = (_Float16)b.y;
  r.h[6] = (_Float16)b.z; r.h[7] = (_Float16)b.w;
  *reinterpret_cast<uint4v*>(xh + idx) = r.u;
}

// ---------------- prepass 2: AWQ dequant -> W' fp16, layout [k/8][n][8] ---
__global__ __launch_bounds__(256) void dequant_w_kernel(const uint32_t* __restrict__ qw,
                                                        const float* __restrict__ sc,
                                                        const uint32_t* __restrict__ qz,
                                                        _Float16* __restrict__ w1) {
  const int T = blockIdx.x * 256 + threadIdx.x;  // 512*1376 threads exactly
  const int qc = T % NQ;
  const int kb8 = T / NQ;                        // k-block of 8
  const int g = kb8 >> 4;                        // group of 128 k

  const uint32_t* qp = qw + (size_t)(kb8 * 8) * NQ + qc;
  uint32_t q[8];
#pragma unroll
  for (int j = 0; j < 8; ++j) q[j] = qp[(size_t)j * NQ];

  const uint32_t zq = qz[(size_t)g * NQ + qc];
  const float* sp = sc + (size_t)g * NN + qc * 8;
  float4 s0 = *reinterpret_cast<const float4*>(sp);
  float4 s1 = *reinterpret_cast<const float4*>(sp + 4);
  const float sv[8] = {s0.x, s0.y, s0.z, s0.w, s1.x, s1.y, s1.z, s1.w};

  _Float16* op = w1 + ((size_t)kb8 * NN + (size_t)qc * 8) * 8;
#pragma unroll
  for (int c = 0; c < 8; ++c) {
    const int sh = ((c >> 1) << 2) + ((c & 1) << 4);  // AWQ col->shift
    uint32_t zc = ((zq >> sh) & 15u) | 0x6400u;       // fp16 1024+z
    zc |= zc << 16;
    U1H2 uz; uz.u = zc;
    const _Float16 hs = (_Float16)sv[c];
    half2v s2 = {hs, hs};
    uint4v outp;
#pragma unroll
    for (int i = 0; i < 4; ++i) {
      const uint32_t lo = (q[2 * i] >> sh) & 15u;
      const uint32_t hi = (q[2 * i + 1] >> sh) & 15u;
      U1H2 uw; uw.u = lo | (hi << 16) | 0x64006400u;
      U1H2 ur; ur.h = (uw.h - uz.h) * s2;             // exact sub, scale
      outp[i] = ur.u;
    }
    *reinterpret_cast<uint4v*>(op + c * 8) = outp;
  }
}

// ---------------- main: read-ahead pipelined GEMM, BK=64 (R10) ------------
// One barrier per phase; each phase's ds_reads feed the NEXT phase's MFMA
// cluster (counted lgkm keeps them in flight), so the 16-MFMA cluster
// overlaps the LDS pipe. Static ping-pong frag sets -- zero register copies.
// vmcnt ledger (2 gloads/stage): VMC(2) at end of even phases retires the
// A+B halves the following odd phase reads. Queue 4-6, never drained.
__global__ __launch_bounds__(512, 2)
void gemm_pipe(const _Float16* __restrict__ xh, const _Float16* __restrict__ w1,
               float* __restrict__ out) {
  __shared__ __align__(16) _Float16 S[65536];   // 128 KB

  const int tid = threadIdx.x;
  const int lane = tid & 63;
  const int wid = tid >> 6;       // 0..7
  const int wm = wid >> 2;        // 0..1  (M half: 128 rows)
  const int wn = wid & 3;         // 0..3  (N quarter: 64 cols)
  const int lr = lane & 15;
  const int lq = lane >> 4;       // k-slot

  // XCD swizzle: XCD owns 2 m-panels x all 43 n-panels, n-major
  const int wg = blockIdx.x;
  const int xcd = wg & 7;
  const int j = wg >> 3;                        // 0..85
  const int m0 = (xcd * 2 + (j & 1)) * BM;
  const int n0 = (j >> 1) * BN;

  // A staging source: chunk c = instr*512+tid; m = c>>2, dest slot q = c&3
  // holds source k-chunk u = q ^ ((m>>1)&3)
  const int c0 = tid, c1 = 512 + tid;
  const _Float16* aS0 = xh + (size_t)(m0 + (c0 >> 2)) * KK
                           + ((c0 & 3) ^ ((c0 >> 3) & 3)) * 8;
  const _Float16* aS1 = xh + (size_t)(m0 + (c1 >> 2)) * KK
                           + ((c1 & 3) ^ ((c1 >> 3) & 3)) * 8;
  // B staging source: kb = c>>8, n = c&255, linear
  const _Float16* bS0 = w1 + ((size_t)(c0 >> 8) * NN + n0 + (c0 & 255)) * 8;
  const _Float16* bS1 = w1 + ((size_t)(c1 >> 8) * NN + n0 + (c1 & 255)) * 8;

  // LDS read offsets (halfs)
  const int sa8 = (lq ^ ((lr >> 1) & 3)) * 8;          // A slot, mi-invariant
  const int vA = (wm * 128 + lr) * 32 + sa8;
  const int vB = lq * 2048 + (wn * 64 + lr) * 8;

  f32x4 acc[8][4];
  const f32x4 fz = {0.f, 0.f, 0.f, 0.f};
#pragma unroll
  for (int i = 0; i < 8; ++i)
#pragma unroll
    for (int jn = 0; jn < 4; ++jn) acc[i][jn] = fz;

  half8 af0[4], af1[4], bf0[4], bf1[4];

#define RD_A4(DST, BUF, KKX, MIH)                                              \
  _Pragma("unroll") for (int mi = 0; mi < 4; ++mi)                             \
      DST[mi] = *reinterpret_cast<const half8*>(                               \
          &S[((BUF) * 2 + (KKX)) * HT + ((MIH) + mi) * 512 + vA]);

#define RD_B4(DST, BUF, KKX)                                                   \
  _Pragma("unroll") for (int ni = 0; ni < 4; ++ni)                             \
      DST[ni] = *reinterpret_cast<const half8*>(                               \
          &S[32768 + ((BUF) * 2 + (KKX)) * HT + ni * 128 + vB]);

#define MF16(ACCH, AREG, BREG)                                                 \
  _Pragma("unroll") for (int mi = 0; mi < 4; ++mi)                             \
      _Pragma("unroll") for (int ni = 0; ni < 4; ++ni)                         \
          acc[(ACCH) + mi][ni] = __builtin_amdgcn_mfma_f32_16x16x32_f16(       \
              AREG[mi], BREG[ni], acc[(ACCH) + mi][ni], 0, 0, 0);

#define STG_A(KKX, BUFX, AOFF)                                                 \
  gload_lds16(aS0 + (AOFF) + (KKX) * 32,                                       \
              &S[((BUFX) * 2 + (KKX)) * HT + wid * 512]);                      \
  gload_lds16(aS1 + (AOFF) + (KKX) * 32,                                       \
              &S[((BUFX) * 2 + (KKX)) * HT + 4096 + wid * 512]);

#define STG_B(KKX, BUFX, BOFF)                                                 \
  gload_lds16(bS0 + (BOFF) + (size_t)(KKX) * NN * 32,                          \
              &S[32768 + ((BUFX) * 2 + (KKX)) * HT + wid * 512]);              \
  gload_lds16(bS1 + (BOFF) + (size_t)(KKX) * NN * 32,                          \
              &S[32768 + ((BUFX) * 2 + (KKX)) * HT + 4096 + wid * 512]);

#define BARRIER __builtin_amdgcn_s_barrier()
#define LGKM(N) asm volatile("s_waitcnt lgkmcnt(" #N ")" ::: "memory")
#define VMC(N) asm volatile("s_waitcnt vmcnt(" #N ")" ::: "memory")
#define SB0 __builtin_amdgcn_sched_barrier(0)
#define PRIO1 __builtin_amdgcn_s_setprio(1)
#define PRIO0 __builtin_amdgcn_s_setprio(0)

  // ---- prologue: stage A0,B0 of tile 0; certify; read cluster-0 frags;
  //      stage A1,B1 of tile 0 (queue = 4 entering the loop) ----
  STG_A(0, 0, 0)
  STG_B(0, 0, 0)
  VMC(0);
  BARRIER; SB0;
  RD_A4(af0, 0, 0, 0)
  RD_B4(bf0, 0, 0)
  STG_A(1, 0, 0)
  STG_B(1, 0, 0)

  for (int it = 0; it < NKT / 2; ++it) {
    const int t0 = it * 2;
    const size_t aO1 = (size_t)((t0 + 1) & (NKT - 1)) * BK;
    const size_t bO1 = (size_t)((t0 + 1) & (NKT - 1)) * ((size_t)NN * 64);
    const size_t aO2 = (size_t)((t0 + 2) & (NKT - 1)) * BK;
    const size_t bO2 = (size_t)((t0 + 2) & (NKT - 1)) * ((size_t)NN * 64);

    // ---- tile t0 (buf 0), staging tile t0+1 into buf 1 ----
    // ph0: MFMA (af0,bf0)->acc[0..3]; read af1 = A(0,kk0,mih4)
    BARRIER; SB0;
    RD_A4(af1, 0, 0, 4)
    STG_A(0, 1, aO1)
    LGKM(4); SB0;
    PRIO1; MF16(0, af0, bf0) PRIO0;
    VMC(2);
    // ph1: MFMA (af1,bf0)->acc[4..7]; read af0 = A(0,kk1,mih0), bf1 = B(0,kk1)
    BARRIER; SB0;
    RD_A4(af0, 0, 1, 0)
    RD_B4(bf1, 0, 1)
    STG_B(0, 1, bO1)
    LGKM(8); SB0;
    PRIO1; MF16(4, af1, bf0) PRIO0;
    // ph2: MFMA (af0,bf1)->acc[0..3]; read af1 = A(0,kk1,mih4)
    BARRIER; SB0;
    RD_A4(af1, 0, 1, 4)
    STG_A(1, 1, aO1)
    LGKM(4); SB0;
    PRIO1; MF16(0, af0, bf1) PRIO0;
    VMC(2);
    // ph3: MFMA (af1,bf1)->acc[4..7]; read af0 = A(1,kk0,mih0), bf0 = B(1,kk0)
    BARRIER; SB0;
    RD_A4(af0, 1, 0, 0)
    RD_B4(bf0, 1, 0)
    STG_B(1, 1, bO1)
    LGKM(8); SB0;
    PRIO1; MF16(4, af1, bf1) PRIO0;

    // ---- tile t0+1 (buf 1), staging tile t0+2 into buf 0 ----
    // ph4
    BARRIER; SB0;
    RD_A4(af1, 1, 0, 4)
    STG_A(0, 0, aO2)
    LGKM(4); SB0;
    PRIO1; MF16(0, af0, bf0) PRIO0;
    VMC(2);
    // ph5
    BARRIER; SB0;
    RD_A4(af0, 1, 1, 0)
    RD_B4(bf1, 1, 1)
    STG_B(0, 0, bO2)
    LGKM(8); SB0;
    PRIO1; MF16(4, af1, bf0) PRIO0;
    // ph6
    BARRIER; SB0;
    RD_A4(af1, 1, 1, 4)
    STG_A(1, 0, aO2)
    LGKM(4); SB0;
    PRIO1; MF16(0, af0, bf1) PRIO0;
    VMC(2);
    // ph7
    BARRIER; SB0;
    RD_A4(af0, 0, 0, 0)
    RD_B4(bf0, 0, 0)
    STG_B(1, 0, bO2)
    LGKM(8); SB0;
    PRIO1; MF16(4, af1, bf1) PRIO0;
  }

#undef RD_A4
#undef RD_B4
#undef MF16
#undef STG_A
#undef STG_B

  // ---- epilogue: C/D layout col=lane&15, row=(lane>>4)*4+i ----
  float* op = out + (size_t)(m0 + wm * 128) * NN + (n0 + wn * 64);
#pragma unroll
  for (int mi = 0; mi < 8; ++mi)
#pragma unroll
    for (int ni = 0; ni < 4; ++ni)
#pragma unroll
      for (int i = 0; i < 4; ++i) {
        const int row = mi * 16 + lq * 4 + i;
        const int col = ni * 16 + lr;
        op[(size_t)row * NN + col] = acc[mi][ni][i];
      }
}

// ---------------- fallback: inline-dequant GEMM (small workspace) ---------
template <bool APRE>
__global__ __launch_bounds__(256)
void awq_gemm(const float* __restrict__ x, const _Float16* __restrict__ xh,
              const uint32_t* __restrict__ qw, const float* __restrict__ sc,
              const uint32_t* __restrict__ qz, float* __restrict__ out) {
  __shared__ __align__(16) _Float16 Asf[128 * 64];
  __shared__ __align__(16) _Float16 Bsf[128 * 64];

  const int tid = threadIdx.x;
  const int lane = tid & 63;
  const int wid = tid >> 6;
  const int wr = wid >> 1;
  const int wc = wid & 1;
  const int n0 = blockIdx.x * 128;
  const int m0 = blockIdx.y * 128;
  const int lr = lane & 15;
  const int lq = lane >> 4;

  const int bn = tid & 127;
  const int bh = tid >> 7;
  const int gn = n0 + bn;
  const int qc = gn >> 3;
  const int jj = gn & 7;
  const int shift = ((jj >> 1) << 2) + ((jj & 1) << 4);

  const int ar = tid >> 1;
  const int ah = tid & 1;

  f32x4 acc[4][4];
  const f32x4 fz = {0.f, 0.f, 0.f, 0.f};
#pragma unroll
  for (int i = 0; i < 4; ++i)
#pragma unroll
    for (int jn = 0; jn < 4; ++jn) acc[i][jn] = fz;

  half2v zsp = {(_Float16)0.f, (_Float16)0.f};
  half2v ssp = {(_Float16)0.f, (_Float16)0.f};

  for (int kt = 0; kt < KK / 64; ++kt) {
    const int k0 = kt * 64;
    if ((kt & 1) == 0) {
      const int g = k0 >> 7;
      const uint32_t zq = qz[(size_t)g * NQ + qc];
      uint32_t zm = ((zq >> shift) & 15u) | 0x6400u;
      zm |= zm << 16;
      U1H2 uz; uz.u = zm; zsp = uz.h;
      const float s = sc[(size_t)g * NN + gn];
      const _Float16 hs = (_Float16)s;
      ssp[0] = hs; ssp[1] = hs;
    }
    __syncthreads();
    if (APRE) {
#pragma unroll
      for (int i = 0; i < 4; ++i) {
        const int cbase = (i * 4 + wid) * 64;
        const int chunk = cbase + lane;
        const int mrow = chunk >> 3;
        const int slot = (chunk & 7) ^ (mrow & 7);
        const _Float16* gp = xh + (size_t)(m0 + mrow) * KK + k0 + slot * 8;
        gload_lds16(gp, (void*)&Asf[cbase * 8]);
      }
    } else {
      const float* xp = x + (size_t)(m0 + ar) * KK + k0 + ah * 32;
#pragma unroll
      for (int j2 = 0; j2 < 4; ++j2) {
        float4 a4 = *reinterpret_cast<const float4*>(xp + j2 * 8);
        float4 b4 = *reinterpret_cast<const float4*>(xp + j2 * 8 + 4);
        U4H8 r;
        r.h[0] = (_Float16)a4.x; r.h[1] = (_Float16)a4.y;
        r.h[2] = (_Float16)a4.z; r.h[3] = (_Float16)a4.w;
        r.h[4] = (_Float16)b4.x; r.h[5] = (_Float16)b4.y;
        r.h[6] = (_Float16)b4.z; r.h[7] = (_Float16)b4.w;
        const int slot = (ah * 4 + j2) ^ (ar & 7);
        *reinterpret_cast<uint4v*>(&Asf[ar * 64 + slot * 8]) = r.u;
      }
    }
    {
      const uint32_t* qp = qw + (size_t)(k0 + bh * 32) * NQ + qc;
#pragma unroll
      for (int f = 0; f < 4; ++f) {
        uint32_t qv[8];
#pragma unroll
        for (int jv = 0; jv < 8; ++jv) qv[jv] = qp[(size_t)(f * 8 + jv) * NQ];
        uint4v wp;
#pragma unroll
        for (int p = 0; p < 4; ++p) {
          const uint32_t lo = (qv[2 * p] >> shift) & 15u;
          const uint32_t hi = (qv[2 * p + 1] >> shift);
          const uint32_t w01 = (((hi << 16) | lo) & 0x000F000Fu) | 0x64006400u;
          U1H2 uw; uw.u = w01;
          U1H2 ur; ur.h = (uw.h - zsp) * ssp;
          wp[p] = ur.u;
        }
        const int slot = (bh * 4 + f) ^ (bn & 7);
        *reinterpret_cast<uint4v*>(&Bsf[bn * 64 + slot * 8]) = wp;
      }
    }
    __syncthreads();
#pragma unroll
    for (int kq = 0; kq < 2; ++kq) {
      half8 af[4], bf[4];
#pragma unroll
      for (int mi = 0; mi < 4; ++mi) {
        const int am = wr * 64 + mi * 16 + lr;
        const int aslot = (kq * 4 + lq) ^ (am & 7);
        af[mi] = *reinterpret_cast<const half8*>(&Asf[am * 64 + aslot * 8]);
      }
#pragma unroll
      for (int ni = 0; ni < 4; ++ni) {
        const int bn2 = wc * 64 + ni * 16 + lr;
        const int bslot = (kq * 4 + lq) ^ (bn2 & 7);
        bf[ni] = *reinterpret_cast<const half8*>(&Bsf[bn2 * 64 + bslot * 8]);
      }
#pragma unroll
      for (int mi = 0; mi < 4; ++mi)
#pragma unroll
        for (int ni = 0; ni < 4; ++ni)
          acc[mi][ni] = __builtin_amdgcn_mfma_f32_16x16x32_f16(af[mi], bf[ni], acc[mi][ni], 0, 0, 0);
    }
  }

  float* op = out + (size_t)(m0 + wr * 64) * NN + (n0 + wc * 64);
#pragma unroll
  for (int mi = 0; mi < 4; ++mi)
#pragma unroll
    for (int ni = 0; ni < 4; ++ni)
#pragma unroll
      for (int i = 0; i < 4; ++i) {
        const int row = mi * 16 + lq * 4 + i;
        const int col = ni * 16 + lr;
        op[(size_t)row * NN + col] = acc[mi][ni][i];
      }
}

extern "C" void kernel_launch(void* const* d_in, const int* in_sizes, int n_in,
                              void* d_out, int out_size, void* d_ws, size_t ws_size,
                              hipStream_t stream) {
  const float* x = (const float*)d_in[0];
  const uint32_t* qw = (const uint32_t*)d_in[1];
  const float* sc = (const float*)d_in[2];
  const uint32_t* qz = (const uint32_t*)d_in[3];
  float* out = (float*)d_out;

  const size_t xh_bytes = (size_t)MM * KK * sizeof(_Float16);   // 33.5 MB
  const size_t w1_bytes = (size_t)KK * NN * sizeof(_Float16);   // 90.2 MB

  if (ws_size >= xh_bytes + w1_bytes) {
    _Float16* xh = (_Float16*)d_ws;
    _Float16* w1 = (_Float16*)((char*)d_ws + xh_bytes);
    convert_x_kernel<<<(MM * KK) / (256 * 8), 256, 0, stream>>>(x, xh);
    dequant_w_kernel<<<(KK / 8) * NQ / 256, 256, 0, stream>>>(qw, sc, qz, w1);
    gemm_pipe<<<NWG, 512, 0, stream>>>(xh, w1, out);
  } else if (ws_size >= xh_bytes) {
    _Float16* xh = (_Float16*)d_ws;
    convert_x_kernel<<<(MM * KK) / (256 * 8), 256, 0, stream>>>(x, xh);
    awq_gemm<true><<<dim3(NN / 128, MM / 128), 256, 0, stream>>>(x, xh, qw, sc, qz, out);
  } else {
    awq_gemm<false><<<dim3(NN / 128, MM / 128), 256, 0, stream>>>(x, nullptr, qw, sc, qz, out);
  }
}